// Round 4
// baseline (313.010 us; speedup 1.0000x reference)
//
#include <hip/hip_runtime.h>

// Weighted BCE over (N=4, C=3, 128^3) fp32.
// Identity (t in {0,1} exactly): t*log(p)+(1-t)*log(1-p) = log(t ? p : 1-p);
// count(t!=0) = sum(t) (float-exact below 2^24).
//
// R3 post-mortem: VGPR_Count=32 proved the compiler re-serialized the batched
// loads (8 live float4 need 32 data VGPRs alone). Latency-bound at 2.6 TB/s.
// R4: loop-free body (exactly 8 static dwordx4 loads per thread), schedule
// pinned with sched_barrier(0) so all loads issue before compute, and 4x the
// block count (6144) for TLP.

#define THREADS 256
#define BLOCKS_PER_SLAB 512
#define NSLABS 12            // N*C = 4*3
#define NCHAN 3
#define LPT 4                // float4 loads per thread per array
// per-slab float4 count: 524288 = BLOCKS_PER_SLAB * THREADS * LPT  (exact)

__device__ __forceinline__ void acc4(float4 p, float4 t, float& lsum, float& lcnt)
{
    float pp[4] = {p.x, p.y, p.z, p.w};
    float tt[4] = {t.x, t.y, t.z, t.w};
#pragma unroll
    for (int k = 0; k < 4; ++k) {
        bool  pos = (tt[k] != 0.0f);
        float x   = pos ? pp[k] : (1.0f - pp[k]);   // cmp + sub + cndmask
        lsum += fmaxf(__logf(x), -100.0f);          // one v_log_f32
        lcnt += tt[k];                               // exact count
    }
}

__global__ __launch_bounds__(THREADS) void bce_partial(
    const float* __restrict__ input,
    const float* __restrict__ target,
    float* __restrict__ bce_sum,    // [3]
    float* __restrict__ ones_cnt)   // [3]
{
    const int slab = blockIdx.x / BLOCKS_PER_SLAB;
    const int blk  = blockIdx.x % BLOCKS_PER_SLAB;
    const int c    = slab % NCHAN;  // block-uniform

    const int S4     = BLOCKS_PER_SLAB * THREADS * LPT;  // 524288
    const int stride = BLOCKS_PER_SLAB * THREADS;        // 131072

    const float4* __restrict__ in4 = (const float4*)input  + (size_t)slab * S4;
    const float4* __restrict__ tg4 = (const float4*)target + (size_t)slab * S4;

    const int i = blk * THREADS + (int)threadIdx.x;

    // 8 independent 16B loads, all issued before any compute.
    float4 p0 = in4[i];
    float4 p1 = in4[i +     stride];
    float4 p2 = in4[i + 2 * stride];
    float4 p3 = in4[i + 3 * stride];
    float4 t0 = tg4[i];
    float4 t1 = tg4[i +     stride];
    float4 t2 = tg4[i + 2 * stride];
    float4 t3 = tg4[i + 3 * stride];
    __builtin_amdgcn_sched_barrier(0);   // nothing crosses: loads stay batched

    float lsum = 0.0f, lcnt = 0.0f;
    acc4(p0, t0, lsum, lcnt);
    acc4(p1, t1, lsum, lcnt);
    acc4(p2, t2, lsum, lcnt);
    acc4(p3, t3, lsum, lcnt);

    // wave (64-lane) reduction
#pragma unroll
    for (int off = 32; off > 0; off >>= 1) {
        lsum += __shfl_down(lsum, off, 64);
        lcnt += __shfl_down(lcnt, off, 64);
    }

    __shared__ float wsum[THREADS / 64];
    __shared__ float wcnt[THREADS / 64];
    const int lane = threadIdx.x & 63;
    const int wave = threadIdx.x >> 6;
    if (lane == 0) { wsum[wave] = lsum; wcnt[wave] = lcnt; }
    __syncthreads();
    if (threadIdx.x == 0) {
        float s = 0.0f, n = 0.0f;
#pragma unroll
        for (int w = 0; w < THREADS / 64; ++w) { s += wsum[w]; n += wcnt[w]; }
        atomicAdd(&bce_sum[c], s);
        atomicAdd(&ones_cnt[c], n);
    }
}

__global__ void bce_final(const float* __restrict__ bce_sum,
                          const float* __restrict__ ones_cnt,
                          float* __restrict__ out,
                          float per_chan_total)
{
    if (threadIdx.x == 0 && blockIdx.x == 0) {
        float acc = 0.0f;
#pragma unroll
        for (int c = 0; c < NCHAN; ++c) {
            float ones = ones_cnt[c];
            float w    = (ones > 0.0f) ? (per_chan_total / fmaxf(ones, 1.0f)) : 1000.0f;
            float bce  = -(bce_sum[c] / per_chan_total);
            acc += w * bce;
        }
        out[0] = acc / (float)NCHAN;
    }
}

extern "C" void kernel_launch(void* const* d_in, const int* in_sizes, int n_in,
                              void* d_out, int out_size, void* d_ws, size_t ws_size,
                              hipStream_t stream)
{
    const float* input  = (const float*)d_in[0];
    const float* target = (const float*)d_in[1];
    float*       out    = (float*)d_out;

    float* bce_sum  = (float*)d_ws;
    float* ones_cnt = (float*)((char*)d_ws + NCHAN * sizeof(float));

    hipMemsetAsync(d_ws, 0, 2 * NCHAN * sizeof(float), stream);

    const long long total = (long long)in_sizes[0];   // 25,165,824
    const float     M     = (float)(total / NCHAN);    // 8,388,608 per channel

    bce_partial<<<NSLABS * BLOCKS_PER_SLAB, THREADS, 0, stream>>>(
        input, target, bce_sum, ones_cnt);
    bce_final<<<1, 64, 0, stream>>>(bce_sum, ones_cnt, out, M);
}

// Round 5
// 211.194 us; speedup vs baseline: 1.4821x; 1.4821x over previous
//
#include <hip/hip_runtime.h>

// Weighted BCE over (N=4, C=3, 128^3) fp32.
// Identity (t in {0,1} exactly): t*log(p)+(1-t)*log(1-p) = log(t ? p : 1-p);
// count(t!=0) = sum(t) (float-exact below 2^24).
//
// R4 post-mortem: WRITE_SIZE scaled 4x with block count (96->384 KB = 32B per
// atomic) and dur rose ~15 ns per extra atomic -> the tail was an ATOMIC
// CONVOY: all-resident blocks finishing together, 2 atomics each, all on ONE
// cache line, serialized across 8 XCDs. R5 removes atomics entirely:
// per-block partials to distinct addresses (plain stores), tiny stage-2
// reduction kernel.

#define THREADS 256
#define BLOCKS_PER_SLAB 128
#define NSLABS 12            // N*C = 4*3
#define NCHAN 3
#define ENTRIES_PER_CHAN (4 * BLOCKS_PER_SLAB)   // 4 slabs per channel -> 512

__device__ __forceinline__ void acc4(float4 p, float4 t, float& lsum, float& lcnt)
{
    float pp[4] = {p.x, p.y, p.z, p.w};
    float tt[4] = {t.x, t.y, t.z, t.w};
#pragma unroll
    for (int k = 0; k < 4; ++k) {
        bool  pos = (tt[k] != 0.0f);
        float x   = pos ? pp[k] : (1.0f - pp[k]);   // cmp + sub + cndmask
        lsum += fmaxf(__logf(x), -100.0f);          // one v_log_f32
        lcnt += tt[k];                               // exact count
    }
}

__global__ __launch_bounds__(THREADS) void bce_partial(
    const float* __restrict__ input,
    const float* __restrict__ target,
    float* __restrict__ psum,    // [3*512] per-block partial bce sums
    float* __restrict__ pcnt,    // [3*512] per-block partial counts
    int S4)                       // float4 elements per slab (524288)
{
    const int slab = blockIdx.x / BLOCKS_PER_SLAB;
    const int blk  = blockIdx.x % BLOCKS_PER_SLAB;
    const int c    = slab % NCHAN;              // block-uniform

    const float4* __restrict__ in4 = (const float4*)input  + (size_t)slab * S4;
    const float4* __restrict__ tg4 = (const float4*)target + (size_t)slab * S4;

    float lsum = 0.0f, lcnt = 0.0f;

    const int stride = BLOCKS_PER_SLAB * THREADS;   // 32768 float4
    int i = blk * THREADS + (int)threadIdx.x;

    for (; i + 3 * stride < S4; i += 4 * stride) {
        float4 p0 = in4[i];
        float4 p1 = in4[i +     stride];
        float4 p2 = in4[i + 2 * stride];
        float4 p3 = in4[i + 3 * stride];
        float4 t0 = tg4[i];
        float4 t1 = tg4[i +     stride];
        float4 t2 = tg4[i + 2 * stride];
        float4 t3 = tg4[i + 3 * stride];
        acc4(p0, t0, lsum, lcnt);
        acc4(p1, t1, lsum, lcnt);
        acc4(p2, t2, lsum, lcnt);
        acc4(p3, t3, lsum, lcnt);
    }
    for (; i < S4; i += stride)   // remainder (none for 524288)
        acc4(in4[i], tg4[i], lsum, lcnt);

    // wave (64-lane) reduction
#pragma unroll
    for (int off = 32; off > 0; off >>= 1) {
        lsum += __shfl_down(lsum, off, 64);
        lcnt += __shfl_down(lcnt, off, 64);
    }

    __shared__ float wsum[THREADS / 64];
    __shared__ float wcnt[THREADS / 64];
    const int lane = threadIdx.x & 63;
    const int wave = threadIdx.x >> 6;
    if (lane == 0) { wsum[wave] = lsum; wcnt[wave] = lcnt; }
    __syncthreads();
    if (threadIdx.x == 0) {
        float s = 0.0f, n = 0.0f;
#pragma unroll
        for (int w = 0; w < THREADS / 64; ++w) { s += wsum[w]; n += wcnt[w]; }
        // channel-contiguous layout: entry within channel = (slab/3)*128 + blk
        const int e = c * ENTRIES_PER_CHAN + (slab / NCHAN) * BLOCKS_PER_SLAB + blk;
        psum[e] = s;          // plain stores, distinct addresses: NO atomics
        pcnt[e] = n;
    }
}

__global__ __launch_bounds__(THREADS) void bce_final(
    const float* __restrict__ psum,
    const float* __restrict__ pcnt,
    float* __restrict__ out,
    float per_chan_total)
{
    const int tid = (int)threadIdx.x;
    float s[NCHAN], n[NCHAN];
#pragma unroll
    for (int c = 0; c < NCHAN; ++c) {
        const int b = c * ENTRIES_PER_CHAN + tid;
        s[c] = psum[b] + psum[b + THREADS];
        n[c] = pcnt[b] + pcnt[b + THREADS];
    }
    // wave reduce all 6 values
#pragma unroll
    for (int off = 32; off > 0; off >>= 1) {
#pragma unroll
        for (int c = 0; c < NCHAN; ++c) {
            s[c] += __shfl_down(s[c], off, 64);
            n[c] += __shfl_down(n[c], off, 64);
        }
    }
    __shared__ float ws[THREADS / 64][NCHAN], wn[THREADS / 64][NCHAN];
    const int lane = tid & 63, wave = tid >> 6;
    if (lane == 0) {
#pragma unroll
        for (int c = 0; c < NCHAN; ++c) { ws[wave][c] = s[c]; wn[wave][c] = n[c]; }
    }
    __syncthreads();
    if (tid == 0) {
        float acc = 0.0f;
#pragma unroll
        for (int c = 0; c < NCHAN; ++c) {
            float ssum = 0.0f, ncnt = 0.0f;
#pragma unroll
            for (int w = 0; w < THREADS / 64; ++w) { ssum += ws[w][c]; ncnt += wn[w][c]; }
            float w8  = (ncnt > 0.0f) ? (per_chan_total / fmaxf(ncnt, 1.0f)) : 1000.0f;
            float bce = -(ssum / per_chan_total);
            acc += w8 * bce;
        }
        out[0] = acc / (float)NCHAN;
    }
}

extern "C" void kernel_launch(void* const* d_in, const int* in_sizes, int n_in,
                              void* d_out, int out_size, void* d_ws, size_t ws_size,
                              hipStream_t stream)
{
    const float* input  = (const float*)d_in[0];
    const float* target = (const float*)d_in[1];
    float*       out    = (float*)d_out;

    const int nentry = NCHAN * ENTRIES_PER_CHAN;          // 1536
    float* psum = (float*)d_ws;
    float* pcnt = (float*)d_ws + nentry;
    // no memset needed: every partial is written by stage 1 before stage 2 reads

    const long long total = (long long)in_sizes[0];        // 25,165,824
    const int       S4    = (int)(total / (NSLABS * 4));    // 524,288
    const float     M     = (float)(total / NCHAN);         // 8,388,608

    bce_partial<<<NSLABS * BLOCKS_PER_SLAB, THREADS, 0, stream>>>(
        input, target, psum, pcnt, S4);
    bce_final<<<1, THREADS, 0, stream>>>(psum, pcnt, out, M);
}